// Round 1
// 927.934 us; speedup vs baseline: 1.0059x; 1.0059x over previous
//
#include <hip/hip_runtime.h>

#define UU 3000
#define SS 1500
#define TT 32
#define BB 16384
#define KK 50
#define RPT 12   // ceil(3000/256) register keys per thread

// order-preserving float<->uint map
__device__ __forceinline__ unsigned int float_to_key(float f) {
    unsigned int b = __float_as_uint(f);
    return (b & 0x80000000u) ? ~b : (b | 0x80000000u);
}
__device__ __forceinline__ float key_to_float(unsigned int k) {
    return (k & 0x80000000u) ? __uint_as_float(k & 0x7FFFFFFFu)
                             : __uint_as_float(~k);
}

// ---------------------------------------------------------------------------
// Kernel 1: per-user top-50 via 4-pass 8-bit radix select, keys in REGISTERS.
// Change this round: 4 per-wave histogram copies. Uniform[-1,1] rows pile
// ~25% of keys into one 8-bit bin (0xBF) in pass 1; a single shared hist
// serializes those same-address LDS atomics across all 256 threads. Per-wave
// copies cut that contention ~4x (only intra-wave serialization remains).
// Block u == UU: classify mask buffer encoding into *flag
//   (0 = int32 words 0/1, 1 = uint8 bytes, 2 = float32 0.0/1.0).
// ---------------------------------------------------------------------------
__global__ __launch_bounds__(256) void topk_select(const float* __restrict__ user_sim,
                                                   int2* __restrict__ topk,
                                                   const unsigned int* __restrict__ mask,
                                                   int* __restrict__ flag) {
    const int u = blockIdx.x;

    if (u == UU) {   // ---- mask-encoding probe ----
        __shared__ int bad_i32, bad_f32;
        if (threadIdx.x == 0) { bad_i32 = 0; bad_f32 = 0; }
        __syncthreads();
        for (int i = threadIdx.x; i < 4096; i += 256) {
            unsigned int w = mask[i];
            if (w > 1u) bad_i32 = 1;
            if (w != 0u && w != 0x3F800000u) bad_f32 = 1;
        }
        __syncthreads();
        if (threadIdx.x == 0) {
            int f = 0;
            if (bad_i32) f = bad_f32 ? 1 : 2;
            *flag = f;
        }
        return;
    }

    __shared__ int hist[4][256];   // one 256-bin copy per wave
    __shared__ int s_bin, s_rem;
    __shared__ int cnt_gt, eq_cnt;
    __shared__ int eq_list[64];

    const float* row = user_sim + (size_t)u * UU;
    const int wcopy = threadIdx.x >> 6;

    unsigned int keys[RPT];
    #pragma unroll
    for (int j = 0; j < RPT; ++j) {
        const int i = threadIdx.x + 256 * j;
        keys[j] = (i < UU) ? float_to_key(row[i]) : 0u;
    }
    if (threadIdx.x == 0) { cnt_gt = 0; eq_cnt = 0; }

    unsigned int prefix = 0u, prefmask = 0u;
    int remaining = KK;

    for (int pass = 0; pass < 4; ++pass) {
        const int shift = 24 - pass * 8;
        hist[0][threadIdx.x] = 0;
        hist[1][threadIdx.x] = 0;
        hist[2][threadIdx.x] = 0;
        hist[3][threadIdx.x] = 0;
        __syncthreads();
        #pragma unroll
        for (int j = 0; j < RPT; ++j) {
            const unsigned int k = keys[j];
            if ((k & prefmask) == prefix)
                atomicAdd(&hist[wcopy][(k >> shift) & 0xFFu], 1);
        }
        __syncthreads();
        // wave 0: suffix-scan 256 bins (4 bins/lane), find threshold bin
        if (threadIdx.x < 64) {
            const int lane = threadIdx.x;
            int h[4];
            #pragma unroll
            for (int b = 0; b < 4; ++b)
                h[b] = hist[0][4 * lane + b] + hist[1][4 * lane + b]
                     + hist[2][4 * lane + b] + hist[3][4 * lane + b];
            const int local = h[0] + h[1] + h[2] + h[3];
            int x = local;                       // inclusive suffix sum over lanes
            for (int off = 1; off < 64; off <<= 1) {
                int y = __shfl_down(x, off, 64);
                if (lane + off < 64) x += y;
            }
            const int excl = x - local;          // keys in strictly higher lane-groups
            if (excl < remaining && remaining <= excl + local) {
                int acc = excl;
                #pragma unroll
                for (int jj = 3; jj >= 0; --jj) {   // descending bins
                    if (acc + h[jj] >= remaining) {
                        s_bin = 4 * lane + jj;
                        s_rem = remaining - acc;
                        break;
                    }
                    acc += h[jj];
                }
            }
        }
        __syncthreads();
        prefix  |= ((unsigned int)s_bin) << shift;
        prefmask |= (0xFFu << shift);
        remaining = s_rem;
        __syncthreads();   // all threads consumed s_bin/s_rem before reuse
    }

    const unsigned int thr = prefix;   // exact key of the boundary element
    #pragma unroll
    for (int j = 0; j < RPT; ++j) {
        const unsigned int k = keys[j];
        const int i = threadIdx.x + 256 * j;
        if (k > thr) {
            int p = atomicAdd(&cnt_gt, 1);
            topk[u * KK + p] = make_int2(i, __float_as_int(key_to_float(k)));
        } else if (k == thr) {
            int e = atomicAdd(&eq_cnt, 1);
            if (e < 64) eq_list[e] = i;
        }
    }
    __syncthreads();
    if (threadIdx.x == 0) {
        // fill slots [KK-remaining, KK) with smallest-index ties (jax tie-break)
        const int n = eq_cnt < 64 ? eq_cnt : 64;
        const int vb = __float_as_int(key_to_float(thr));
        const int base = KK - remaining;
        for (int r = 0; r < remaining; ++r) {
            int mi = -1, mv = 0x7FFFFFFF;
            for (int jj = 0; jj < n; ++jj) {
                int v = eq_list[jj];
                if (v >= 0 && v < mv) { mv = v; mi = jj; }
            }
            eq_list[mi] = -1;
            topk[u * KK + base + r] = make_int2(mv, vb);
        }
    }
}

// ---------------------------------------------------------------------------
// Kernel 2: one 64-lane wave per batch element. Lanes 0..49 gather one
// neighbor each (pair load + 3 independent scattered loads), butterfly-
// reduce sim_sum / dev_sum across the wave.
// Change this round: non-temporal loads for the streaming qos/mask gathers
// (576/144 MB arrays, ~0 line reuse) so they don't thrash L2/L3 and evict
// avg (18 MB) / topk (1.2 MB), which have real ~5.5x per-user reuse.
// ---------------------------------------------------------------------------
__global__ __launch_bounds__(256) void gather_kernel(
    const float* __restrict__ qos, const void* __restrict__ mask,
    const float* __restrict__ avg, const int* __restrict__ time_ids,
    const int* __restrict__ user_ids, const int* __restrict__ service_ids,
    const int2* __restrict__ topk, const int* __restrict__ flag,
    float* __restrict__ out) {

    const int wave = (int)((blockIdx.x * blockDim.x + threadIdx.x) >> 6);
    const int lane = (int)(threadIdx.x & 63);
    if (wave >= BB) return;

    const int u = user_ids[wave];
    const int s = service_ids[wave];
    const int t = time_ids[wave];
    const float base = avg[(size_t)u * SS + s];
    const int fl = *flag;   // wave-uniform, L2-hot

    float wv = 0.0f, dv = 0.0f;
    if (lane < KK) {
        const int2  tv  = topk[u * KK + lane];
        const int   idx = tv.x;
        const float val = __int_as_float(tv.y);
        const size_t off3 = ((size_t)idx * SS + s) * TT + t;
        const float q = __builtin_nontemporal_load(qos + off3);  // streaming
        const float a = avg[(size_t)idx * SS + s];               // cache-resident
        int m;
        if (fl == 0)       m = __builtin_nontemporal_load((const int*)mask + off3);
        else if (fl == 1)  m = (int)__builtin_nontemporal_load((const unsigned char*)mask + off3);
        else               m = (__builtin_nontemporal_load((const float*)mask + off3) != 0.0f) ? 1 : 0;
        wv = m ? val : 0.0f;
        dv = m ? val * (q - a) : 0.0f;
    }
    for (int m2 = 32; m2 >= 1; m2 >>= 1) {
        wv += __shfl_xor(wv, m2, 64);
        dv += __shfl_xor(dv, m2, 64);
    }
    if (lane == 0) {
        const float deviation = (wv > 0.0f) ? (dv / wv) : 0.0f;
        const float r = base + deviation;
        __builtin_nontemporal_store((r > 0.0f) ? r : 0.0f, out + wave);
    }
}

extern "C" void kernel_launch(void* const* d_in, const int* in_sizes, int n_in,
                              void* d_out, int out_size, void* d_ws, size_t ws_size,
                              hipStream_t stream) {
    const float* qos      = (const float*)d_in[0];
    const void*  mask     = d_in[1];
    const float* avg      = (const float*)d_in[2];
    const float* user_sim = (const float*)d_in[3];
    const int* time_ids    = (const int*)d_in[4];
    const int* user_ids    = (const int*)d_in[5];
    const int* service_ids = (const int*)d_in[6];
    float* out = (float*)d_out;

    // ws layout: [topk pairs: U*K int2][flag: int]
    int2* topk = (int2*)d_ws;
    int*  flag = (int*)((char*)d_ws + (size_t)UU * KK * 8);

    topk_select<<<UU + 1, 256, 0, stream>>>(user_sim, topk,
                                            (const unsigned int*)mask, flag);
    gather_kernel<<<(BB * 64) / 256, 256, 0, stream>>>(
        qos, mask, avg, time_ids, user_ids, service_ids, topk, flag, out);
}